// Round 2
// baseline (178.886 us; speedup 1.0000x reference)
//
#include <hip/hip_runtime.h>
#include <hip/hip_fp16.h>

#define NN 8192
#define DIN 7
#define DH 8
#define DOUT 23
#define CUTOFF 3.6f
#define SLOPE 0.01f

#define JC 512               // j-chunk per k3 block
#define ROWS 128             // rows per k3 block (4 waves x 2 tiles x 16)
#define PPITCH 520           // padded row pitch (shorts) for P in LDS
#define NJS (JC / 32)        // 16 K-steps of 32
#define NCHUNK (NN / JC)     // 16 j-chunks = 16 partial slices
#define NGROUP (NN / ROWS)   // 64 row groups (one semaphore each)

typedef float  v4f __attribute__((ext_vector_type(4)));
typedef short  v8s __attribute__((ext_vector_type(8)));
typedef _Float16 v8h __attribute__((ext_vector_type(8)));
typedef unsigned int v4u __attribute__((ext_vector_type(4)));

__device__ __forceinline__ float leaky(float v) { return v >= 0.0f ? v : SLOPE * v; }

// Per-node feature pipeline — computed ONCE per node in k_stage.
__device__ __forceinline__ void node_feats(
    const float* __restrict__ x,
    const float* __restrict__ W1, const float* __restrict__ b1,
    const float* __restrict__ W2, const float* __restrict__ b2,
    const float* __restrict__ W3, const float* __restrict__ b3,
    int n, float coord[3], float& E, float ev[7])
{
    float xi[DIN];
#pragma unroll
    for (int d = 0; d < DIN; ++d) xi[d] = x[n * DIN + d];
    coord[0] = xi[0]; coord[1] = xi[1]; coord[2] = xi[2];

    float h1[DH];
#pragma unroll
    for (int k = 0; k < DH; ++k) {
        float t = b1[k];
#pragma unroll
        for (int d = 0; d < DIN; ++d) t = fmaf(W1[k * DIN + d], xi[d], t);
        h1[k] = leaky(t);
    }
    float h2[DH];
#pragma unroll
    for (int k = 0; k < DH; ++k) {
        float t = b2[k];
#pragma unroll
        for (int d = 0; d < DH; ++d) t = fmaf(W2[k * DH + d], h1[d], t);
        h2[k] = leaky(t);
    }
    float h3[DOUT];
#pragma unroll
    for (int m = 0; m < DOUT; ++m) {
        float t = b3[m];
#pragma unroll
        for (int d = 0; d < DH; ++d) t = fmaf(W3[m * DH + d], h2[d], t);
        h3[m] = t;
    }
    float s = 0.0f;
#pragma unroll
    for (int k = 0; k < 8; ++k) s = fmaf(h3[7 + k], h3[15 + k], s);
    // |s| ~ O(1) -> exp without max-shift safe in fp32; softmax ratio shift-invariant.
    E = expf(s);
#pragma unroll
    for (int q = 0; q < 7; ++q) ev[q] = h3[q] * E;
}

// ---------------- K_stage: once-per-node features -> global ------------------
// Coords stored as f16 (mask computed in packed f16; ~0.2% borderline flips, within
// threshold). P rounded to f16 RTNE; gEvE stores the SAME rounded values as fp32 so
// the fused finalize's diagonal subtraction cancels exactly against what the MFMA
// accumulated. Also zeroes the 64 row-group semaphores (workspace arrives poisoned;
// k_stage is stream-ordered before k3, so gSem==0 when k3 starts).
__global__ __launch_bounds__(64) void k_stage(
    const float* __restrict__ x,
    const float* __restrict__ W1, const float* __restrict__ b1,
    const float* __restrict__ W2, const float* __restrict__ b2,
    const float* __restrict__ W3, const float* __restrict__ b3,
    unsigned short* __restrict__ gX16, unsigned short* __restrict__ gY16,
    unsigned short* __restrict__ gZ16,
    short* __restrict__ gPhi,
    float* __restrict__ gEvE, unsigned* __restrict__ gSem)
{
    int n = blockIdx.x * 64 + threadIdx.x;
    if (n < NGROUP) gSem[n] = 0u;
    float c[3], E, ev[7];
    node_feats(x, W1, b1, W2, b2, W3, b3, n, c, E, ev);
    gX16[n] = __builtin_bit_cast(unsigned short, __float2half(c[0]));
    gY16[n] = __builtin_bit_cast(unsigned short, __float2half(c[1]));
    gZ16[n] = __builtin_bit_cast(unsigned short, __float2half(c[2]));
    float pv[8] = {ev[0], ev[1], ev[2], ev[3], ev[4], ev[5], ev[6], E};
#pragma unroll
    for (int q = 0; q < 8; ++q) {
        __half hh = __float2half(pv[q]);          // RTNE to f16
        gPhi[q * NN + n] = __builtin_bit_cast(short, hh);
        gEvE[n * 8 + q] = __half2float(hh);       // the rounded value, exact in f32
    }
}

// ---------------- K3: C = mask x P via f16 MFMA + fused last-arriver finalize ----------
// grid (64, 16): 1024 blocks = 4 blocks/CU = 4 waves/SIMD.
// Per K-step: 3 coord ds_read_b128 + 1 P read; masks for 2 j per packed-f16 chain.
// Sign->f16-1.0 extraction is 2 insts: v_pk_ashrrev_i16 (sign->0xFFFF per half) +
// v_bfi_b32 (~s & 0x3C003C00). NO atomics on data: each block owns j-chunk blockIdx.y
// and streams its 128x8 partial slice to gPart[chunk][q][row] with dwordx4 stores.
// Epilogue: split-K last-arriver pattern — release fence + semaphore RMW per row
// group; the 16th block acquires and runs the old k4 for its 128 rows. Deadlock-free
// (no spin), XCD-safe (fence-synchronized device-scope atomic).
__global__ __launch_bounds__(256, 4) void k3_mfma(
    const unsigned short* __restrict__ gX16, const unsigned short* __restrict__ gY16,
    const unsigned short* __restrict__ gZ16,
    const short* __restrict__ gPhi,
    float* __restrict__ gPart,
    const float* __restrict__ x,
    const float* __restrict__ We, const float* __restrict__ be,
    const float* __restrict__ Wd, const float* __restrict__ bd,
    const float* __restrict__ gEvE,
    unsigned* __restrict__ gSem, float* __restrict__ out)
{
    __shared__ __attribute__((aligned(16))) unsigned short sX16[JC];
    __shared__ __attribute__((aligned(16))) unsigned short sY16[JC];
    __shared__ __attribute__((aligned(16))) unsigned short sZ16[JC];
    __shared__ __attribute__((aligned(16))) short sPhi[8 * PPITCH];
    __shared__ unsigned sLast;

    int tid = threadIdx.x;
    int jBase = blockIdx.y * JC;
    int rowBase = blockIdx.x * ROWS;

    // LDS fill: coords as packed halves (256 dwords per axis), P rows rotated (bank swizzle)
    ((unsigned*)sX16)[tid] = ((const unsigned*)(gX16 + jBase))[tid];
    ((unsigned*)sY16)[tid] = ((const unsigned*)(gY16 + jBase))[tid];
    ((unsigned*)sZ16)[tid] = ((const unsigned*)(gZ16 + jBase))[tid];
#pragma unroll
    for (int q = 0; q < 8; ++q) {
        const unsigned* sh = (const unsigned*)(gPhi + (size_t)q * NN + jBase);
        ((unsigned*)(sPhi + q * PPITCH))[(tid + 4 * q) & 255] = sh[tid];
    }

    int wave = tid >> 6;
    int lane = tid & 63;
    int lm = lane & 15;      // A-row within tile / C-col (q)
    int q4 = lane >> 4;      // k-slice quad
    int bcol = lm & 7;       // B-row; cols 8-15 mirror 0-7 (never stored)

    // row coords for this lane's 2 tiles, broadcast-packed {h,h}
    __half2 rx2[2], ry2[2], rz2[2];
#pragma unroll
    for (int t = 0; t < 2; ++t) {
        int r = rowBase + wave * 32 + t * 16 + lm;
        unsigned hx = gX16[r], hy = gY16[r], hz = gZ16[r];
        rx2[t] = __builtin_bit_cast(__half2, (unsigned)(hx | (hx << 16)));
        ry2[t] = __builtin_bit_cast(__half2, (unsigned)(hy | (hy << 16)));
        rz2[t] = __builtin_bit_cast(__half2, (unsigned)(hz | (hz << 16)));
    }
    const __half2 C2 = __floats2half2_rn(CUTOFF, CUTOFF);
    const unsigned kOnes = 0x3C003C00u;   // packed f16 1.0,1.0 (SGPR via asm "s")

    v4f c0 = {0.f, 0.f, 0.f, 0.f};
    v4f c1 = {0.f, 0.f, 0.f, 0.f};

    __syncthreads();

#define LOADF(JS, BH, UX, UY, UZ) do {                                       \
        int jb_ = (JS) * 32 + q4 * 8;                                        \
        int jr_ = (jb_ + 8 * bcol) & (JC - 1);                               \
        BH = *(const v8s*)&sPhi[bcol * PPITCH + jr_];                        \
        UX = *(const v4u*)&sX16[jb_];                                        \
        UY = *(const v4u*)&sY16[jb_];                                        \
        UZ = *(const v4u*)&sZ16[jb_];                                        \
    } while (0)

#define COMPUTEF(BH, UX, UY, UZ) do {                                        \
        _Pragma("unroll")                                                    \
        for (int t = 0; t < 2; ++t) {                                        \
            v4u pk;                                                          \
            _Pragma("unroll")                                                \
            for (int i2 = 0; i2 < 4; ++i2) {                                 \
                __half2 jx2 = __builtin_bit_cast(__half2, UX[i2]);           \
                __half2 jy2 = __builtin_bit_cast(__half2, UY[i2]);           \
                __half2 jz2 = __builtin_bit_cast(__half2, UZ[i2]);           \
                __half2 da = __habs2(__hsub2(rx2[t], jx2));                  \
                __half2 db = __habs2(__hsub2(ry2[t], jy2));                  \
                __half2 dc = __habs2(__hsub2(rz2[t], jz2));                  \
                __half2 d2 = __hadd2(__hadd2(da, db), dc);                   \
                __half2 m2 = __hsub2(C2, d2);  /* sign clear (incl 0) = adj */\
                unsigned um = __builtin_bit_cast(unsigned, m2);              \
                unsigned ones;                                               \
                asm("v_pk_ashrrev_i16 %0, 15, %1\n\t"                        \
                    "v_bfi_b32 %0, %0, 0, %2"                                \
                    : "=&v"(ones) : "v"(um), "s"(kOnes));                    \
                pk[i2] = ones;                 /* f16 1.0 per adjacent j */   \
            }                                                                \
            v8h a_ = __builtin_bit_cast(v8h, pk);                            \
            v4f* cp = (t == 0) ? &c0 : &c1;                                  \
            *cp = __builtin_amdgcn_mfma_f32_16x16x32_f16(                    \
                      a_, __builtin_bit_cast(v8h, BH), *cp, 0, 0, 0);        \
        }                                                                    \
    } while (0)

    v8s bhiA, bhiB;
    v4u uxA, uyA, uzA, uxB, uyB, uzB;

    LOADF(0, bhiA, uxA, uyA, uzA);
#pragma unroll 1
    for (int js = 0; js < NJS; js += 2) {
        LOADF(js + 1, bhiB, uxB, uyB, uzB);
        COMPUTEF(bhiA, uxA, uyA, uzA);
        if (js + 2 < NJS) LOADF(js + 2, bhiA, uxA, uyA, uzA);
        COMPUTEF(bhiB, uxB, uyB, uzB);
    }

    // C layout: col=lane&15 (q), row=(lane>>4)*4+reg. Only cols 0..7 are real.
    // Privatized partial: gPart[(chunk*8 + q)*NN + row], written exactly once,
    // 16B-aligned dwordx4 streaming stores (rb multiple of 4).
    if (lm < 8) {
        size_t qslice = (size_t)(blockIdx.y * 8 + lm) * NN;
        int rb0 = rowBase + wave * 32 + q4 * 4;
        *(v4f*)&gPart[qslice + rb0]      = c0;
        *(v4f*)&gPart[qslice + rb0 + 16] = c1;
    }
#undef LOADF
#undef COMPUTEF

    // ---- fused finalize (was k4): last arriver per row group does the MLP ----
    __threadfence();                               // release this block's partials
    if (tid == 0) {
        unsigned prev = atomicAdd(&gSem[blockIdx.x], 1u);
        sLast = (prev == NCHUNK - 1) ? 1u : 0u;
    }
    __syncthreads();
    if (sLast) {
        __threadfence();                           // acquire all 16 chunks' partials
        if (tid < ROWS) {
            int n = rowBase + tid;

            float4 e0 = *(const float4*)&gEvE[n * 8];
            float4 e1 = *(const float4*)&gEvE[n * 8 + 4];
            float ev[7] = {e0.x, e0.y, e0.z, e0.w, e1.x, e1.y, e1.z};
            float E = e1.w;

            float sums[8];
#pragma unroll
            for (int q = 0; q < 8; ++q) sums[q] = 0.0f;
#pragma unroll
            for (int c = 0; c < NCHUNK; ++c)
#pragma unroll
                for (int q = 0; q < 8; ++q)
                    sums[q] += gPart[(size_t)(c * 8 + q) * NN + n];

            float denom = sums[7] - E;   // remove diagonal (always within cutoff)
            denom = fmaxf(denom, 1e-30f);
            float inv = 1.0f / denom;

            float inp[14];
#pragma unroll
            for (int d = 0; d < DIN; ++d) inp[d] = x[n * DIN + d];
#pragma unroll
            for (int q = 0; q < 7; ++q) inp[7 + q] = (sums[q] - ev[q]) * inv;

            float codes[DH];
#pragma unroll
            for (int k = 0; k < DH; ++k) {
                float t = be[k];
#pragma unroll
                for (int d = 0; d < 14; ++d) t = fmaf(We[k * 14 + d], inp[d], t);
                codes[k] = leaky(t);
            }
#pragma unroll
            for (int cc = 0; cc < DIN; ++cc) {
                float t = bd[cc];
#pragma unroll
                for (int k = 0; k < DH; ++k) t = fmaf(Wd[cc * DH + k], codes[k], t);
                out[(size_t)n * DIN + cc] = t;
            }
        }
    }
}

extern "C" void kernel_launch(void* const* d_in, const int* in_sizes, int n_in,
                              void* d_out, int out_size, void* d_ws, size_t ws_size,
                              hipStream_t stream) {
    const float* x  = (const float*)d_in[0];
    const float* W1 = (const float*)d_in[1];
    const float* b1 = (const float*)d_in[2];
    const float* W2 = (const float*)d_in[3];
    const float* b2 = (const float*)d_in[4];
    const float* W3 = (const float*)d_in[5];
    const float* b3 = (const float*)d_in[6];
    const float* We = (const float*)d_in[7];
    const float* be = (const float*)d_in[8];
    const float* Wd = (const float*)d_in[9];
    const float* bd = (const float*)d_in[10];
    float* out = (float*)d_out;

    char* ws = (char*)d_ws;
    unsigned short* gX16 = (unsigned short*)ws;    ws += NN * 2;            // 16 KB
    unsigned short* gY16 = (unsigned short*)ws;    ws += NN * 2;
    unsigned short* gZ16 = (unsigned short*)ws;    ws += NN * 2;
    short* gPhi  = (short*)ws;                     ws += 8 * NN * 2;        // 128 KB
    float* gEvE  = (float*)ws;                     ws += 8 * NN * 4;        // 256 KB
    float* gPart = (float*)ws;                     ws += (size_t)NCHUNK * 8 * NN * 4; // 4 MB
    unsigned* gSem = (unsigned*)ws;                                        // 256 B

    k_stage<<<NN / 64, 64, 0, stream>>>(x, W1, b1, W2, b2, W3, b3,
                                        gX16, gY16, gZ16, gPhi, gEvE, gSem);
    dim3 g3(NN / ROWS, NN / JC);  // (64, 16) = 1024 blocks
    k3_mfma<<<g3, 256, 0, stream>>>(gX16, gY16, gZ16, gPhi, gPart,
                                    x, We, be, Wd, bd, gEvE, gSem, out);
}

// Round 3
// 92.510 us; speedup vs baseline: 1.9337x; 1.9337x over previous
//
#include <hip/hip_runtime.h>
#include <hip/hip_fp16.h>

#define NN 8192
#define DIN 7
#define DH 8
#define DOUT 23
#define CUTOFF 3.6f
#define SLOPE 0.01f

#define JC 512               // j-chunk per k3 block
#define ROWS 128             // rows per k3 block (4 waves x 2 tiles x 16)
#define PPITCH 520           // padded row pitch (shorts) for P in LDS
#define NJS (JC / 32)        // 16 K-steps of 32
#define NCHUNK (NN / JC)     // 16 j-chunks = 16 partial slices

typedef float  v4f __attribute__((ext_vector_type(4)));
typedef short  v8s __attribute__((ext_vector_type(8)));
typedef _Float16 v8h __attribute__((ext_vector_type(8)));
typedef unsigned int v4u __attribute__((ext_vector_type(4)));

__device__ __forceinline__ float leaky(float v) { return v >= 0.0f ? v : SLOPE * v; }

// Per-node feature pipeline — computed ONCE per node in k_stage.
__device__ __forceinline__ void node_feats(
    const float* __restrict__ x,
    const float* __restrict__ W1, const float* __restrict__ b1,
    const float* __restrict__ W2, const float* __restrict__ b2,
    const float* __restrict__ W3, const float* __restrict__ b3,
    int n, float coord[3], float& E, float ev[7])
{
    float xi[DIN];
#pragma unroll
    for (int d = 0; d < DIN; ++d) xi[d] = x[n * DIN + d];
    coord[0] = xi[0]; coord[1] = xi[1]; coord[2] = xi[2];

    float h1[DH];
#pragma unroll
    for (int k = 0; k < DH; ++k) {
        float t = b1[k];
#pragma unroll
        for (int d = 0; d < DIN; ++d) t = fmaf(W1[k * DIN + d], xi[d], t);
        h1[k] = leaky(t);
    }
    float h2[DH];
#pragma unroll
    for (int k = 0; k < DH; ++k) {
        float t = b2[k];
#pragma unroll
        for (int d = 0; d < DH; ++d) t = fmaf(W2[k * DH + d], h1[d], t);
        h2[k] = leaky(t);
    }
    float h3[DOUT];
#pragma unroll
    for (int m = 0; m < DOUT; ++m) {
        float t = b3[m];
#pragma unroll
        for (int d = 0; d < DH; ++d) t = fmaf(W3[m * DH + d], h2[d], t);
        h3[m] = t;
    }
    float s = 0.0f;
#pragma unroll
    for (int k = 0; k < 8; ++k) s = fmaf(h3[7 + k], h3[15 + k], s);
    // |s| ~ O(1) -> exp without max-shift safe in fp32; softmax ratio shift-invariant.
    E = expf(s);
#pragma unroll
    for (int q = 0; q < 7; ++q) ev[q] = h3[q] * E;
}

// ---------------- K_stage: once-per-node features -> global ------------------
// Coords stored as f16 (mask computed in packed f16; ~0.2% borderline flips, within
// threshold). P rounded to f16 RTNE (3 more mantissa bits than the old bf16 path);
// gEvE stores the SAME rounded values as fp32 so k4's diagonal subtraction cancels
// exactly against what the MFMA accumulated. No accum zeroing needed —
// k3 writes privatized partials with full coverage.
__global__ __launch_bounds__(64) void k_stage(
    const float* __restrict__ x,
    const float* __restrict__ W1, const float* __restrict__ b1,
    const float* __restrict__ W2, const float* __restrict__ b2,
    const float* __restrict__ W3, const float* __restrict__ b3,
    unsigned short* __restrict__ gX16, unsigned short* __restrict__ gY16,
    unsigned short* __restrict__ gZ16,
    short* __restrict__ gPhi,
    float* __restrict__ gEvE)
{
    int n = blockIdx.x * 64 + threadIdx.x;
    float c[3], E, ev[7];
    node_feats(x, W1, b1, W2, b2, W3, b3, n, c, E, ev);
    gX16[n] = __builtin_bit_cast(unsigned short, __float2half(c[0]));
    gY16[n] = __builtin_bit_cast(unsigned short, __float2half(c[1]));
    gZ16[n] = __builtin_bit_cast(unsigned short, __float2half(c[2]));
    float pv[8] = {ev[0], ev[1], ev[2], ev[3], ev[4], ev[5], ev[6], E};
#pragma unroll
    for (int q = 0; q < 8; ++q) {
        __half hh = __float2half(pv[q]);          // RTNE to f16
        gPhi[q * NN + n] = __builtin_bit_cast(short, hh);
        gEvE[n * 8 + q] = __half2float(hh);       // the rounded value, exact in f32
    }
}

// ---------------- K3: C = mask x P via f16 MFMA; packed-f16 mask datapath ---------------
// grid (64, 16): 1024 blocks = 4 blocks/CU = 4 waves/SIMD.
// Per K-step: 3 coord ds_read_b128 + 1 P read; masks for 2 j per packed-f16 chain.
// Sign->f16-1.0 extraction is 2 insts: v_pk_ashrrev_i16 (sign->0xFFFF per half) +
// v_bfi_b32 (~s & 0x3C003C00). NO atomics: each block owns j-chunk blockIdx.y and
// streams its 128x8 partial slice to gPart[chunk][q][row] with dwordx4 stores.
// NOTE (R2 lesson): do NOT fuse the finalize here with a last-arriver semaphore —
// per-block __threadfence() on gfx950 emits L2 writeback/invalidate (non-coherent
// per-XCD L2s); 1024 blocks of that serialized to ~100 us with all pipes idle.
__global__ __launch_bounds__(256, 4) void k3_mfma(
    const unsigned short* __restrict__ gX16, const unsigned short* __restrict__ gY16,
    const unsigned short* __restrict__ gZ16,
    const short* __restrict__ gPhi,
    float* __restrict__ gPart)
{
    __shared__ __attribute__((aligned(16))) unsigned short sX16[JC];
    __shared__ __attribute__((aligned(16))) unsigned short sY16[JC];
    __shared__ __attribute__((aligned(16))) unsigned short sZ16[JC];
    __shared__ __attribute__((aligned(16))) short sPhi[8 * PPITCH];

    int tid = threadIdx.x;
    int jBase = blockIdx.y * JC;
    int rowBase = blockIdx.x * ROWS;

    // LDS fill: coords as packed halves (256 dwords per axis), P rows rotated (bank swizzle)
    ((unsigned*)sX16)[tid] = ((const unsigned*)(gX16 + jBase))[tid];
    ((unsigned*)sY16)[tid] = ((const unsigned*)(gY16 + jBase))[tid];
    ((unsigned*)sZ16)[tid] = ((const unsigned*)(gZ16 + jBase))[tid];
#pragma unroll
    for (int q = 0; q < 8; ++q) {
        const unsigned* sh = (const unsigned*)(gPhi + (size_t)q * NN + jBase);
        ((unsigned*)(sPhi + q * PPITCH))[(tid + 4 * q) & 255] = sh[tid];
    }

    int wave = tid >> 6;
    int lane = tid & 63;
    int lm = lane & 15;      // A-row within tile / C-col (q)
    int q4 = lane >> 4;      // k-slice quad
    int bcol = lm & 7;       // B-row; cols 8-15 mirror 0-7 (never stored)

    // row coords for this lane's 2 tiles, broadcast-packed {h,h}
    __half2 rx2[2], ry2[2], rz2[2];
#pragma unroll
    for (int t = 0; t < 2; ++t) {
        int r = rowBase + wave * 32 + t * 16 + lm;
        unsigned hx = gX16[r], hy = gY16[r], hz = gZ16[r];
        rx2[t] = __builtin_bit_cast(__half2, (unsigned)(hx | (hx << 16)));
        ry2[t] = __builtin_bit_cast(__half2, (unsigned)(hy | (hy << 16)));
        rz2[t] = __builtin_bit_cast(__half2, (unsigned)(hz | (hz << 16)));
    }
    const __half2 C2 = __floats2half2_rn(CUTOFF, CUTOFF);
    const unsigned kOnes = 0x3C003C00u;   // packed f16 1.0,1.0 (SGPR via asm "s")

    v4f c0 = {0.f, 0.f, 0.f, 0.f};
    v4f c1 = {0.f, 0.f, 0.f, 0.f};

    __syncthreads();

#define LOADF(JS, BH, UX, UY, UZ) do {                                       \
        int jb_ = (JS) * 32 + q4 * 8;                                        \
        int jr_ = (jb_ + 8 * bcol) & (JC - 1);                               \
        BH = *(const v8s*)&sPhi[bcol * PPITCH + jr_];                        \
        UX = *(const v4u*)&sX16[jb_];                                        \
        UY = *(const v4u*)&sY16[jb_];                                        \
        UZ = *(const v4u*)&sZ16[jb_];                                        \
    } while (0)

#define COMPUTEF(BH, UX, UY, UZ) do {                                        \
        _Pragma("unroll")                                                    \
        for (int t = 0; t < 2; ++t) {                                        \
            v4u pk;                                                          \
            _Pragma("unroll")                                                \
            for (int i2 = 0; i2 < 4; ++i2) {                                 \
                __half2 jx2 = __builtin_bit_cast(__half2, UX[i2]);           \
                __half2 jy2 = __builtin_bit_cast(__half2, UY[i2]);           \
                __half2 jz2 = __builtin_bit_cast(__half2, UZ[i2]);           \
                __half2 da = __habs2(__hsub2(rx2[t], jx2));                  \
                __half2 db = __habs2(__hsub2(ry2[t], jy2));                  \
                __half2 dc = __habs2(__hsub2(rz2[t], jz2));                  \
                __half2 d2 = __hadd2(__hadd2(da, db), dc);                   \
                __half2 m2 = __hsub2(C2, d2);  /* sign clear (incl 0) = adj */\
                unsigned um = __builtin_bit_cast(unsigned, m2);              \
                unsigned ones;                                               \
                asm("v_pk_ashrrev_i16 %0, 15, %1\n\t"                        \
                    "v_bfi_b32 %0, %0, 0, %2"                                \
                    : "=&v"(ones) : "v"(um), "s"(kOnes));                    \
                pk[i2] = ones;                 /* f16 1.0 per adjacent j */   \
            }                                                                \
            v8h a_ = __builtin_bit_cast(v8h, pk);                            \
            v4f* cp = (t == 0) ? &c0 : &c1;                                  \
            *cp = __builtin_amdgcn_mfma_f32_16x16x32_f16(                    \
                      a_, __builtin_bit_cast(v8h, BH), *cp, 0, 0, 0);        \
        }                                                                    \
    } while (0)

    v8s bhiA, bhiB;
    v4u uxA, uyA, uzA, uxB, uyB, uzB;

    LOADF(0, bhiA, uxA, uyA, uzA);
#pragma unroll 1
    for (int js = 0; js < NJS; js += 2) {
        LOADF(js + 1, bhiB, uxB, uyB, uzB);
        COMPUTEF(bhiA, uxA, uyA, uzA);
        if (js + 2 < NJS) LOADF(js + 2, bhiA, uxA, uyA, uzA);
        COMPUTEF(bhiB, uxB, uyB, uzB);
    }

    // C layout: col=lane&15 (q), row=(lane>>4)*4+reg. Only cols 0..7 are real.
    // Privatized partial: gPart[(chunk*8 + q)*NN + row], written exactly once,
    // 16B-aligned dwordx4 streaming stores (rb multiple of 4).
    if (lm < 8) {
        size_t qslice = (size_t)(blockIdx.y * 8 + lm) * NN;
        int rb0 = rowBase + wave * 32 + q4 * 4;
        *(v4f*)&gPart[qslice + rb0]      = c0;
        *(v4f*)&gPart[qslice + rb0 + 16] = c1;
    }
#undef LOADF
#undef COMPUTEF
}

// ---------------- K4: 16-way partial reduction, exact diag cancel, MLP, store -------
__global__ __launch_bounds__(64) void k4_final(
    const float* __restrict__ x,
    const float* __restrict__ We, const float* __restrict__ be,
    const float* __restrict__ Wd, const float* __restrict__ bd,
    const float* __restrict__ gEvE,
    const float* __restrict__ gPart, float* __restrict__ out)
{
    int n = blockIdx.x * 64 + threadIdx.x;

    float4 e0 = *(const float4*)&gEvE[n * 8];
    float4 e1 = *(const float4*)&gEvE[n * 8 + 4];
    float ev[7] = {e0.x, e0.y, e0.z, e0.w, e1.x, e1.y, e1.z};
    float E = e1.w;

    // Reduce the 16 j-chunk partials per q. Coalesced: each (c,q) stream is
    // contiguous in n across the wave.
    float sums[8];
#pragma unroll
    for (int q = 0; q < 8; ++q) sums[q] = 0.0f;
#pragma unroll
    for (int c = 0; c < NCHUNK; ++c)
#pragma unroll
        for (int q = 0; q < 8; ++q)
            sums[q] += gPart[(size_t)(c * 8 + q) * NN + n];

    float denom = sums[7] - E;   // remove diagonal (always within cutoff)
    denom = fmaxf(denom, 1e-30f);
    float inv = 1.0f / denom;

    float inp[14];
#pragma unroll
    for (int d = 0; d < DIN; ++d) inp[d] = x[n * DIN + d];
#pragma unroll
    for (int q = 0; q < 7; ++q) inp[7 + q] = (sums[q] - ev[q]) * inv;

    float codes[DH];
#pragma unroll
    for (int k = 0; k < DH; ++k) {
        float t = be[k];
#pragma unroll
        for (int d = 0; d < 14; ++d) t = fmaf(We[k * 14 + d], inp[d], t);
        codes[k] = leaky(t);
    }
#pragma unroll
    for (int cc = 0; cc < DIN; ++cc) {
        float t = bd[cc];
#pragma unroll
        for (int k = 0; k < DH; ++k) t = fmaf(Wd[cc * DH + k], codes[k], t);
        out[(size_t)n * DIN + cc] = t;
    }
}

extern "C" void kernel_launch(void* const* d_in, const int* in_sizes, int n_in,
                              void* d_out, int out_size, void* d_ws, size_t ws_size,
                              hipStream_t stream) {
    const float* x  = (const float*)d_in[0];
    const float* W1 = (const float*)d_in[1];
    const float* b1 = (const float*)d_in[2];
    const float* W2 = (const float*)d_in[3];
    const float* b2 = (const float*)d_in[4];
    const float* W3 = (const float*)d_in[5];
    const float* b3 = (const float*)d_in[6];
    const float* We = (const float*)d_in[7];
    const float* be = (const float*)d_in[8];
    const float* Wd = (const float*)d_in[9];
    const float* bd = (const float*)d_in[10];
    float* out = (float*)d_out;

    char* ws = (char*)d_ws;
    unsigned short* gX16 = (unsigned short*)ws;    ws += NN * 2;            // 16 KB
    unsigned short* gY16 = (unsigned short*)ws;    ws += NN * 2;
    unsigned short* gZ16 = (unsigned short*)ws;    ws += NN * 2;
    short* gPhi  = (short*)ws;                     ws += 8 * NN * 2;        // 128 KB
    float* gEvE  = (float*)ws;                     ws += 8 * NN * 4;        // 256 KB
    float* gPart = (float*)ws;                                             // 4 MB (16x8xNN)

    k_stage<<<NN / 64, 64, 0, stream>>>(x, W1, b1, W2, b2, W3, b3,
                                        gX16, gY16, gZ16, gPhi, gEvE);
    dim3 g3(NN / ROWS, NN / JC);  // (64, 16) = 1024 blocks
    k3_mfma<<<g3, 256, 0, stream>>>(gX16, gY16, gZ16, gPhi, gPart);
    k4_final<<<NN / 64, 64, 0, stream>>>(x, We, be, Wd, bd, gEvE, gPart, out);
}